// Round 2
// baseline (255.919 us; speedup 1.0000x reference)
//
#include <hip/hip_runtime.h>

#define Bdim 16
#define Ndim 8192
#define Fdim 256
#define ROWS (Bdim * Ndim)                    // 131072
#define CHUNKS_PER_ROW (Fdim / 4)             // 64 float4 chunks per row
#define TOTAL_CHUNKS (ROWS * CHUNKS_PER_ROW)  // 8388608

#define REDUCE_BLOCKS 512
#define NORM_BLOCKS 8192
#define EPS 1e-3f

// ws layout (floats): [0..255]=sum  [256..511]=sumsq  [512..767]=scale  [768..1023]=bias

__global__ __launch_bounds__(512) void init_kernel(float* __restrict__ ws) {
    ws[threadIdx.x] = 0.0f;  // zero sum+sumsq (512 floats); ws is re-poisoned to 0xAA each call
}

__global__ __launch_bounds__(256) void reduce_kernel(
    const float* __restrict__ x, const int* __restrict__ nv,
    float* __restrict__ ws)
{
    __shared__ float lds_s[4][Fdim];
    __shared__ float lds_q[4][Fdim];
    __shared__ int s_nv[Bdim];
    const int tid = threadIdx.x;
    if (tid < Bdim) s_nv[tid] = nv[tid];
    __syncthreads();

    const int c = tid & 63;      // float4 chunk within row (fixed per thread)
    const int r = tid >> 6;      // row slot 0..3
    const int f0 = c * 4;

    float sum0 = 0.f, sum1 = 0.f, sum2 = 0.f, sum3 = 0.f;
    float sq0 = 0.f, sq1 = 0.f, sq2 = 0.f, sq3 = 0.f;

    const int rows_per_block = ROWS / REDUCE_BLOCKS;  // 256
    const int row0 = blockIdx.x * rows_per_block;
    for (int i = r; i < rows_per_block; i += 4) {
        const int row = row0 + i;
        const int b = row >> 13;           // row / 8192
        const int n = row & (Ndim - 1);
        if (n < s_nv[b]) {                 // invalid rows: never read
            const float4 v = *((const float4*)(x + (size_t)row * Fdim) + c);
            sum0 += v.x; sq0 += v.x * v.x;
            sum1 += v.y; sq1 += v.y * v.y;
            sum2 += v.z; sq2 += v.z * v.z;
            sum3 += v.w; sq3 += v.w * v.w;
        }
    }

    lds_s[r][f0 + 0] = sum0; lds_s[r][f0 + 1] = sum1;
    lds_s[r][f0 + 2] = sum2; lds_s[r][f0 + 3] = sum3;
    lds_q[r][f0 + 0] = sq0;  lds_q[r][f0 + 1] = sq1;
    lds_q[r][f0 + 2] = sq2;  lds_q[r][f0 + 3] = sq3;
    __syncthreads();

    float ts = 0.0f, tq = 0.0f;
    #pragma unroll
    for (int rr = 0; rr < 4; rr++) { ts += lds_s[rr][tid]; tq += lds_q[rr][tid]; }
    unsafeAtomicAdd(&ws[tid], ts);          // hw global_atomic_add_f32, device scope
    unsafeAtomicAdd(&ws[Fdim + tid], tq);
}

__global__ __launch_bounds__(256) void finalize_kernel(
    const int* __restrict__ nv, const float* __restrict__ gamma,
    const float* __restrict__ beta, float* __restrict__ ws)
{
    __shared__ float s_count;
    const int tid = threadIdx.x;
    if (tid == 0) {
        int cnt = 0;
        for (int i = 0; i < Bdim; i++) cnt += nv[i];
        s_count = fmaxf((float)cnt, 1.0f);
    }
    __syncthreads();
    const float inv_count = 1.0f / s_count;
    const float mean = ws[tid] * inv_count;
    float var = ws[Fdim + tid] * inv_count - mean * mean;
    var = fmaxf(var, 0.0f);
    const float inv_std = rsqrtf(var + EPS);
    const float s = inv_std * gamma[tid];
    ws[2 * Fdim + tid] = s;
    ws[3 * Fdim + tid] = beta[tid] - mean * s;
}

__global__ __launch_bounds__(256) void norm_kernel(
    const float* __restrict__ x, const int* __restrict__ nv,
    const float* __restrict__ ws, float* __restrict__ out)
{
    __shared__ int s_nv[Bdim];
    const int tid = threadIdx.x;
    if (tid < Bdim) s_nv[tid] = nv[tid];

    // chunk index c = idx & 63 is loop-invariant (stride % 64 == 0):
    // this thread's 4 scale/bias values live in registers, no LDS traffic.
    const int c = tid & 63;
    const float4 sc = ((const float4*)(ws + 2 * Fdim))[c];
    const float4 bi = ((const float4*)(ws + 3 * Fdim))[c];
    __syncthreads();

    const int base = blockIdx.x * 256 + tid;
    const int stride = NORM_BLOCKS * 256;                      // 2097152
    #pragma unroll
    for (int it = 0; it < TOTAL_CHUNKS / (NORM_BLOCKS * 256); it++) {  // 4 iters
        const int idx = base + it * stride;
        const int row = idx >> 6;          // 64 chunks per row
        const int b = row >> 13;
        const int n = row & (Ndim - 1);
        float4* po = (float4*)out + idx;
        if (n < s_nv[b]) {
            const float4 v = ((const float4*)x)[idx];
            float4 o;
            o.x = fmaf(v.x, sc.x, bi.x);
            o.y = fmaf(v.y, sc.y, bi.y);
            o.z = fmaf(v.z, sc.z, bi.z);
            o.w = fmaf(v.w, sc.w, bi.w);
            *po = o;
        } else {
            *po = make_float4(0.f, 0.f, 0.f, 0.f);  // padded rows zeroed
        }
    }
}

extern "C" void kernel_launch(void* const* d_in, const int* in_sizes, int n_in,
                              void* d_out, int out_size, void* d_ws, size_t ws_size,
                              hipStream_t stream) {
    const float* x     = (const float*)d_in[0];   // f32 [16,8192,256]
    const int*   nv    = (const int*)d_in[1];     // int32 [16]
    const float* gamma = (const float*)d_in[2];   // f32 [256]
    const float* beta  = (const float*)d_in[3];   // f32 [256]
    float* out = (float*)d_out;
    float* ws  = (float*)d_ws;

    init_kernel<<<1, 512, 0, stream>>>(ws);
    reduce_kernel<<<REDUCE_BLOCKS, 256, 0, stream>>>(x, nv, ws);
    finalize_kernel<<<1, 256, 0, stream>>>(nv, gamma, beta, ws);
    norm_kernel<<<NORM_BLOCKS, 256, 0, stream>>>(x, nv, ws, out);
}

// Round 4
// 235.030 us; speedup vs baseline: 1.0889x; 1.0889x over previous
//
#include <hip/hip_runtime.h>

#define Bdim 16
#define Ndim 8192
#define Fdim 256
#define EPS 1e-3f

#define RED_BLOCKS_PER_BATCH 64                        // 8192 rows / 64 = 128 rows/block
#define RED_BLOCKS (Bdim * RED_BLOCKS_PER_BATCH)       // 1024 blocks = 4/CU
#define RED_ROWS_PER_BLOCK (Ndim / RED_BLOCKS_PER_BATCH)  // 128

#define NORM_BLOCKS 8192
#define TOTAL_CHUNKS (Bdim * Ndim * (Fdim / 4))        // 8388608 float4 chunks

typedef float fx4 __attribute__((ext_vector_type(4)));  // native vector: ok for nontemporal builtins

// ws layout (floats): [0..255]=sum  [256..511]=sumsq

__global__ __launch_bounds__(512) void init_kernel(float* __restrict__ ws) {
    ws[threadIdx.x] = 0.0f;   // ws is re-poisoned to 0xAA before every timed call
}

__global__ __launch_bounds__(256) void reduce_kernel(
    const float* __restrict__ x, const int* __restrict__ nv,
    float* __restrict__ ws)
{
    __shared__ float lds_s[4][Fdim];
    __shared__ float lds_q[4][Fdim];
    const int tid = threadIdx.x;
    const int b   = blockIdx.x >> 6;                        // 64 blocks per batch
    const int rb0 = (blockIdx.x & 63) * RED_ROWS_PER_BLOCK; // first row-in-batch
    const int nvb = nv[b];                                  // wave-uniform scalar
    int valid = nvb - rb0;                                  // rows this block must read
    valid = valid < 0 ? 0 : (valid > RED_ROWS_PER_BLOCK ? RED_ROWS_PER_BLOCK : valid);

    const int c = tid & 63;      // float4 chunk within row (wave spans one full row)
    const int r = tid >> 6;      // row slot 0..3
    const fx4* xb = (const fx4*)(x + ((size_t)b * Ndim + rb0) * Fdim) + c;

    float s0=0.f,s1=0.f,s2=0.f,s3=0.f, q0=0.f,q1=0.f,q2=0.f,q3=0.f;

    int i = r;
    // 4 independent loads in flight per wave — no per-row branch, pure streaming
    for (; i + 12 < valid; i += 16) {
        const fx4 v0 = xb[(size_t)(i     ) * 64];
        const fx4 v1 = xb[(size_t)(i +  4) * 64];
        const fx4 v2 = xb[(size_t)(i +  8) * 64];
        const fx4 v3 = xb[(size_t)(i + 12) * 64];
        s0 += v0.x; q0 += v0.x*v0.x;  s1 += v0.y; q1 += v0.y*v0.y;
        s2 += v0.z; q2 += v0.z*v0.z;  s3 += v0.w; q3 += v0.w*v0.w;
        s0 += v1.x; q0 += v1.x*v1.x;  s1 += v1.y; q1 += v1.y*v1.y;
        s2 += v1.z; q2 += v1.z*v1.z;  s3 += v1.w; q3 += v1.w*v1.w;
        s0 += v2.x; q0 += v2.x*v2.x;  s1 += v2.y; q1 += v2.y*v2.y;
        s2 += v2.z; q2 += v2.z*v2.z;  s3 += v2.w; q3 += v2.w*v2.w;
        s0 += v3.x; q0 += v3.x*v3.x;  s1 += v3.y; q1 += v3.y*v3.y;
        s2 += v3.z; q2 += v3.z*v3.z;  s3 += v3.w; q3 += v3.w*v3.w;
    }
    for (; i < valid; i += 4) {
        const fx4 v = xb[(size_t)i * 64];
        s0 += v.x; q0 += v.x*v.x;  s1 += v.y; q1 += v.y*v.y;
        s2 += v.z; q2 += v.z*v.z;  s3 += v.w; q3 += v.w*v.w;
    }

    const int f0 = c * 4;
    lds_s[r][f0+0]=s0; lds_s[r][f0+1]=s1; lds_s[r][f0+2]=s2; lds_s[r][f0+3]=s3;
    lds_q[r][f0+0]=q0; lds_q[r][f0+1]=q1; lds_q[r][f0+2]=q2; lds_q[r][f0+3]=q3;
    __syncthreads();

    float ts = 0.0f, tq = 0.0f;
    #pragma unroll
    for (int rr = 0; rr < 4; rr++) { ts += lds_s[rr][tid]; tq += lds_q[rr][tid]; }
    unsafeAtomicAdd(&ws[tid], ts);          // hw global_atomic_add_f32, device scope
    unsafeAtomicAdd(&ws[Fdim + tid], tq);
}

// finalize fused into norm: each of the 256 threads recomputes its feature's
// scale/bias from the ws sums (L2-hot: 2 KiB per block), stages via LDS.
__global__ __launch_bounds__(256) void norm_kernel(
    const float* __restrict__ x, const int* __restrict__ nv,
    const float* __restrict__ gamma, const float* __restrict__ beta,
    const float* __restrict__ ws, float* __restrict__ out)
{
    __shared__ float s_sc[Fdim], s_bi[Fdim];
    __shared__ int s_nv[Bdim];
    const int tid = threadIdx.x;
    if (tid < Bdim) s_nv[tid] = nv[tid];
    __syncthreads();
    {
        int cnt = 0;
        #pragma unroll
        for (int i = 0; i < Bdim; i++) cnt += s_nv[i];
        const float inv_count = 1.0f / fmaxf((float)cnt, 1.0f);
        const float mean = ws[tid] * inv_count;
        float var = fmaf(ws[Fdim + tid], inv_count, -mean * mean);
        var = fmaxf(var, 0.0f);
        const float s = rsqrtf(var + EPS) * gamma[tid];
        s_sc[tid] = s;
        s_bi[tid] = fmaf(-mean, s, beta[tid]);
    }
    __syncthreads();

    // chunk index c = idx & 63 is loop-invariant (stride % 64 == 0):
    // this thread's 4 scale/bias values live in registers.
    const int c = tid & 63;
    const fx4 sc = ((const fx4*)s_sc)[c];
    const fx4 bi = ((const fx4*)s_bi)[c];

    const int base = blockIdx.x * 256 + tid;
    const int stride = NORM_BLOCKS * 256;                      // 2097152
    #pragma unroll
    for (int it = 0; it < TOTAL_CHUNKS / (NORM_BLOCKS * 256); it++) {  // 4 iters
        const int idx = base + it * stride;
        const int row = idx >> 6;          // 64 chunks per row; wave = one row
        const int b = row >> 13;
        const int n = row & (Ndim - 1);
        fx4* po = (fx4*)out + idx;
        if (n < s_nv[b]) {                 // wave-uniform branch
            const fx4 v = ((const fx4*)x)[idx];
            fx4 o;
            o.x = fmaf(v.x, sc.x, bi.x);
            o.y = fmaf(v.y, sc.y, bi.y);
            o.z = fmaf(v.z, sc.z, bi.z);
            o.w = fmaf(v.w, sc.w, bi.w);
            __builtin_nontemporal_store(o, po);   // out is write-only: don't pollute L2/L3
        } else {
            const fx4 z = {0.f, 0.f, 0.f, 0.f};
            __builtin_nontemporal_store(z, po);
        }
    }
}

extern "C" void kernel_launch(void* const* d_in, const int* in_sizes, int n_in,
                              void* d_out, int out_size, void* d_ws, size_t ws_size,
                              hipStream_t stream) {
    const float* x     = (const float*)d_in[0];   // f32 [16,8192,256]
    const int*   nv    = (const int*)d_in[1];     // int32 [16]
    const float* gamma = (const float*)d_in[2];   // f32 [256]
    const float* beta  = (const float*)d_in[3];   // f32 [256]
    float* out = (float*)d_out;
    float* ws  = (float*)d_ws;

    init_kernel<<<1, 512, 0, stream>>>(ws);
    reduce_kernel<<<RED_BLOCKS, 256, 0, stream>>>(x, nv, ws);
    norm_kernel<<<NORM_BLOCKS, 256, 0, stream>>>(x, nv, gamma, beta, ws, out);
}